// Round 1
// baseline (433.231 us; speedup 1.0000x reference)
//
#include <hip/hip_runtime.h>

#define F 128
#define SCAN_TILE 1024

// prep: repack W into Wq (chunked-interleaved for the fused matvec), zero counts,
// zero the work-steal cursor. Replaces transpose_w + zero_int (one launch).
// Wq layout (floats): for k-chunk c=k>>2, r=k&3, o2=o&63, h=o>>6:
//   Wq[c*512 + o2*8 + r*2 + h] = W[o*128 + k]
// => lane o2 reads 32B contiguous per chunk = 2 coalesced float4s.
__global__ void prep_kernel(const float* __restrict__ W, float* __restrict__ Wq,
                            int* __restrict__ counts, int* __restrict__ wcur, int N) {
    int i = blockIdx.x * 256 + threadIdx.x;
    if (i < F * F) {
        int o = i >> 7, k = i & 127;
        int c = k >> 2, r = k & 3, o2 = o & 63, h = o >> 6;
        Wq[c * 512 + o2 * 8 + r * 2 + h] = W[i];
    }
    if (i < N) counts[i] = 0;
    if (i == 0) *wcur = 0;
}

__global__ void zero_f4_kernel(float4* __restrict__ out, int n4) {
    int i = blockIdx.x * blockDim.x + threadIdx.x;
    if (i < n4) out[i] = make_float4(0.f, 0.f, 0.f, 0.f);
}

__global__ void hist_kernel(const int* __restrict__ dst, int* __restrict__ counts, int E) {
    int e = blockIdx.x * blockDim.x + threadIdx.x;
    if (e < E) atomicAdd(&counts[dst[e]], 1);
}

// Two-level scan. scan1: per-tile (1024 elems) exclusive scan + tile totals.
__global__ __launch_bounds__(256) void scan1_kernel(const int* __restrict__ counts,
                                                    int* __restrict__ offsets,
                                                    int* __restrict__ blockSums, int N) {
    __shared__ int lds[256];
    const int tid = threadIdx.x;
    const int i0 = blockIdx.x * SCAN_TILE + tid * 4;
    int v[4];
    int s = 0;
#pragma unroll
    for (int j = 0; j < 4; ++j) {
        int i = i0 + j;
        v[j] = (i < N) ? counts[i] : 0;
        s += v[j];
    }
    lds[tid] = s;
    __syncthreads();
    for (int off = 1; off < 256; off <<= 1) {
        int t = (tid >= off) ? lds[tid - off] : 0;
        __syncthreads();
        lds[tid] += t;
        __syncthreads();
    }
    int excl = lds[tid] - s;
#pragma unroll
    for (int j = 0; j < 4; ++j) {
        int i = i0 + j;
        if (i < N) offsets[i] = excl;
        excl += v[j];
    }
    if (tid == 255) blockSums[blockIdx.x] = lds[255];
}

__global__ __launch_bounds__(256) void scan2_kernel(int* __restrict__ blockSums,
                                                    int* __restrict__ offsets, int NB, int N) {
    __shared__ int lds[256];
    const int tid = threadIdx.x;
    int s = (tid < NB) ? blockSums[tid] : 0;
    lds[tid] = s;
    __syncthreads();
    for (int off = 1; off < 256; off <<= 1) {
        int t = (tid >= off) ? lds[tid - off] : 0;
        __syncthreads();
        lds[tid] += t;
        __syncthreads();
    }
    if (tid < NB) blockSums[tid] = lds[tid] - s;
    if (tid == 255) offsets[N] = lds[255];
}

__global__ __launch_bounds__(256) void scan3_kernel(int* __restrict__ offsets,
                                                    int* __restrict__ cursor,
                                                    const int* __restrict__ blockSums, int N) {
    int i = blockIdx.x * blockDim.x + threadIdx.x;
    if (i < N) {
        int o = offsets[i] + blockSums[i / SCAN_TILE];
        offsets[i] = o;
        cursor[i] = o;
    }
}

__global__ void place_kernel(const int* __restrict__ src, const int* __restrict__ dst,
                             int* __restrict__ cursor, int* __restrict__ ssrc, int E) {
    int e = blockIdx.x * blockDim.x + threadIdx.x;
    if (e < E) {
        int pos = atomicAdd(&cursor[dst[e]], 1);
        ssrc[pos] = src[e];
    }
}

// Fused aggregate + linear + relu.
// One wave processes a batch of 4 nodes (work-stealing via global cursor):
//   phase 1 (proven agg loop): gather+sum each node's edges; half-wave pairs with
//     float4 loads, cross-half shuffle combine; half 0 writes the 128-float row
//     into a per-wave LDS buffer (wave-local, s_waitcnt lgkmcnt(0) ordering only —
//     no block barrier, waves stay independent).
//   phase 2: matvec for 4 nodes against Wq (global, L2-hot, coalesced 32B/lane per
//     k-chunk, amortized over 4 nodes); lane computes outputs {lane, lane+64};
//     agg values broadcast from LDS (same-address b128 reads = conflict-free).
// Matvec VALU (~10 us aggregate) + LDS hide under the BW-bound gather (VALUBusy 11%).
__global__ __launch_bounds__(256) void agg_linear_kernel(
        const float* __restrict__ feat,
        const int* __restrict__ ssrc,
        const int* __restrict__ offs,
        const float* __restrict__ Wq,
        const float* __restrict__ bias,
        int* __restrict__ wcur,
        float* __restrict__ out, int N) {
    __shared__ __align__(16) float abuf[4][512];   // 4 waves x 4 nodes x 128 floats = 8 KB
    const int wid  = threadIdx.x >> 6;
    const int lane = threadIdx.x & 63;
    const int half = lane >> 5;
    const int q    = lane & 31;
    const int nbatch = (N + 3) >> 2;
    const float4* feat4 = (const float4*)feat;
    const float4* WqL = ((const float4*)Wq) + (lane << 1);
    float* buf = abuf[wid];
    const float b0 = bias[lane];
    const float b1 = bias[64 + lane];

    for (;;) {
        int bidx;
        if (lane == 0) bidx = atomicAdd(wcur, 1);
        bidx = __shfl(bidx, 0);
        if (bidx >= nbatch) break;
        const int v0 = bidx << 2;
        const int nv = min(4, N - v0);

        // ---- phase 1: aggregate nv nodes into LDS ----
        for (int t = 0; t < nv; ++t) {
            const int s0 = offs[v0 + t], s1 = offs[v0 + t + 1];
            float ax = 0.f, ay = 0.f, az = 0.f, aw = 0.f;
            int e = s0 + half;
            for (; e + 6 < s1; e += 8) {   // 4 edges per half = 8 edges/wave/iter
                int i0 = ssrc[e], i1 = ssrc[e + 2], i2 = ssrc[e + 4], i3 = ssrc[e + 6];
                const float4 f0 = feat4[(size_t)i0 * 32 + q];
                const float4 f1 = feat4[(size_t)i1 * 32 + q];
                const float4 f2 = feat4[(size_t)i2 * 32 + q];
                const float4 f3 = feat4[(size_t)i3 * 32 + q];
                ax += (f0.x + f1.x) + (f2.x + f3.x);
                ay += (f0.y + f1.y) + (f2.y + f3.y);
                az += (f0.z + f1.z) + (f2.z + f3.z);
                aw += (f0.w + f1.w) + (f2.w + f3.w);
            }
            for (; e < s1; e += 2) {
                const float4 f0 = feat4[(size_t)ssrc[e] * 32 + q];
                ax += f0.x; ay += f0.y; az += f0.z; aw += f0.w;
            }
            ax += __shfl_xor(ax, 32);
            ay += __shfl_xor(ay, 32);
            az += __shfl_xor(az, 32);
            aw += __shfl_xor(aw, 32);
            if (half == 0) {
                float4 r;
                r.x = ax; r.y = ay; r.z = az; r.w = aw;
                ((float4*)(buf + (t << 7)))[q] = r;
            }
        }
        // wave-local ordering: all this wave's ds_writes complete before reads
        asm volatile("s_waitcnt lgkmcnt(0)" ::: "memory");

        // ---- phase 2: out[v][o] = relu(b[o] + sum_k agg[v][k]*W[o][k]) ----
        float acc00 = 0.f, acc01 = 0.f, acc10 = 0.f, acc11 = 0.f;
        float acc20 = 0.f, acc21 = 0.f, acc30 = 0.f, acc31 = 0.f;
#pragma unroll 2
        for (int c = 0; c < 32; ++c) {
            const float4 wa = WqL[c * 128];       // {W[o][k],W[o+64][k],W[o][k+1],W[o+64][k+1]}
            const float4 wb = WqL[c * 128 + 1];   // k+2, k+3
            const int k = c << 2;
            const float4 a0 = *(const float4*)(buf + k);          // LDS broadcast
            const float4 a1 = *(const float4*)(buf + 128 + k);
            const float4 a2 = *(const float4*)(buf + 256 + k);
            const float4 a3 = *(const float4*)(buf + 384 + k);
            acc00 += a0.x * wa.x + a0.y * wa.z + a0.z * wb.x + a0.w * wb.z;
            acc01 += a0.x * wa.y + a0.y * wa.w + a0.z * wb.y + a0.w * wb.w;
            acc10 += a1.x * wa.x + a1.y * wa.z + a1.z * wb.x + a1.w * wb.z;
            acc11 += a1.x * wa.y + a1.y * wa.w + a1.z * wb.y + a1.w * wb.w;
            acc20 += a2.x * wa.x + a2.y * wa.z + a2.z * wb.x + a2.w * wb.z;
            acc21 += a2.x * wa.y + a2.y * wa.w + a2.z * wb.y + a2.w * wb.w;
            acc30 += a3.x * wa.x + a3.y * wa.z + a3.z * wb.x + a3.w * wb.z;
            acc31 += a3.x * wa.y + a3.y * wa.w + a3.z * wb.y + a3.w * wb.w;
        }

        float* o0 = out + (size_t)v0 * F;
        o0[lane]      = fmaxf(acc00 + b0, 0.f);
        o0[64 + lane] = fmaxf(acc01 + b1, 0.f);
        if (nv > 1) {
            o0[F + lane]      = fmaxf(acc10 + b0, 0.f);
            o0[F + 64 + lane] = fmaxf(acc11 + b1, 0.f);
        }
        if (nv > 2) {
            o0[2 * F + lane]      = fmaxf(acc20 + b0, 0.f);
            o0[2 * F + 64 + lane] = fmaxf(acc21 + b1, 0.f);
        }
        if (nv > 3) {
            o0[3 * F + lane]      = fmaxf(acc30 + b0, 0.f);
            o0[3 * F + 64 + lane] = fmaxf(acc31 + b1, 0.f);
        }
    }
}

// ---------------- fallback path (ws too small): R1-proven ----------------
__global__ void scatter_atomic_kernel(const float* __restrict__ feat,
                                      const int* __restrict__ src,
                                      const int* __restrict__ dst,
                                      float* __restrict__ agg, int E) {
    int gid = blockIdx.x * blockDim.x + threadIdx.x;
    int e = gid >> 5;
    if (e >= E) return;
    int q = gid & 31;
    int s = src[e];
    int d = dst[e];
    const float4 v = ((const float4*)(feat + (size_t)s * F))[q];
    float* o = agg + (size_t)d * F + (q << 2);
    atomicAdd(o + 0, v.x);
    atomicAdd(o + 1, v.y);
    atomicAdd(o + 2, v.z);
    atomicAdd(o + 3, v.w);
}

__global__ __launch_bounds__(256) void linear_relu_w_kernel(
        float* __restrict__ h, const float* __restrict__ W,
        const float* __restrict__ b, int N) {
    __shared__ __align__(16) float sA[64][132];
    const int tid = threadIdx.x;
    const int row0 = blockIdx.x * 64;

    for (int i = tid; i < 64 * 32; i += 256) {
        int r = i >> 5, q = i & 31;
        int gr = row0 + r;
        float4 v = make_float4(0.f, 0.f, 0.f, 0.f);
        if (gr < N) v = ((const float4*)(h + (size_t)gr * F))[q];
        *((float4*)&sA[r][q << 2]) = v;
    }
    __syncthreads();

    const int tr = tid >> 5;
    const int tc = tid & 31;
    float acc[8][4];
#pragma unroll
    for (int i = 0; i < 8; ++i)
#pragma unroll
        for (int j = 0; j < 4; ++j) acc[i][j] = 0.f;

    const float* Wr0 = W + (size_t)(tc * 4 + 0) * F;
    const float* Wr1 = W + (size_t)(tc * 4 + 1) * F;
    const float* Wr2 = W + (size_t)(tc * 4 + 2) * F;
    const float* Wr3 = W + (size_t)(tc * 4 + 3) * F;

    for (int k = 0; k < F; k += 4) {
        const float4 w0 = *(const float4*)&Wr0[k];
        const float4 w1 = *(const float4*)&Wr1[k];
        const float4 w2 = *(const float4*)&Wr2[k];
        const float4 w3 = *(const float4*)&Wr3[k];
#pragma unroll
        for (int i = 0; i < 8; ++i) {
            const float4 a = *(const float4*)&sA[tr * 8 + i][k];
            acc[i][0] += a.x * w0.x + a.y * w0.y + a.z * w0.z + a.w * w0.w;
            acc[i][1] += a.x * w1.x + a.y * w1.y + a.z * w1.z + a.w * w1.w;
            acc[i][2] += a.x * w2.x + a.y * w2.y + a.z * w2.z + a.w * w2.w;
            acc[i][3] += a.x * w3.x + a.y * w3.y + a.z * w3.z + a.w * w3.w;
        }
    }

    const float4 bias = ((const float4*)b)[tc];
#pragma unroll
    for (int i = 0; i < 8; ++i) {
        int gr = row0 + tr * 8 + i;
        if (gr < N) {
            float4 o;
            o.x = fmaxf(acc[i][0] + bias.x, 0.f);
            o.y = fmaxf(acc[i][1] + bias.y, 0.f);
            o.z = fmaxf(acc[i][2] + bias.z, 0.f);
            o.w = fmaxf(acc[i][3] + bias.w, 0.f);
            ((float4*)(h + (size_t)gr * F))[tc] = o;
        }
    }
}

extern "C" void kernel_launch(void* const* d_in, const int* in_sizes, int n_in,
                              void* d_out, int out_size, void* d_ws, size_t ws_size,
                              hipStream_t stream) {
    const float* feat = (const float*)d_in[0];
    const int*   src  = (const int*)d_in[1];
    const int*   dst  = (const int*)d_in[2];
    const float* W    = (const float*)d_in[3];
    const float* b    = (const float*)d_in[4];
    float* out = (float*)d_out;

    const int N = in_sizes[0] / F;   // 50000
    const int E = in_sizes[1];       // 800000
    const int NB = (N + SCAN_TILE - 1) / SCAN_TILE;  // 49 (<=256)

    // ws layout (4B elems): counts[N] | offsets[N+1] | cursor[N] | blockSums[256]
    //                     | wcur[4] | ssrc[E] | pad | Wq[128*128] (16B-aligned)
    const size_t ints_before = (size_t)N + (N + 1) + N + 256 + 4 + E;
    const size_t wq_off = (ints_before + 3) & ~(size_t)3;
    const size_t ws_needed = (wq_off + (size_t)F * F) * sizeof(int);

    if (ws_size >= ws_needed && NB <= 256) {
        int* counts    = (int*)d_ws;
        int* offsets   = counts + N;
        int* cursor    = offsets + (N + 1);
        int* blockSums = cursor + N;
        int* wcur      = blockSums + 256;
        int* ssrc      = wcur + 4;
        float* Wq      = (float*)d_ws + wq_off;

        prep_kernel<<<(N + 255) / 256, 256, 0, stream>>>(W, Wq, counts, wcur, N);
        hist_kernel<<<(E + 255) / 256, 256, 0, stream>>>(dst, counts, E);
        scan1_kernel<<<NB, 256, 0, stream>>>(counts, offsets, blockSums, N);
        scan2_kernel<<<1, 256, 0, stream>>>(blockSums, offsets, NB, N);
        scan3_kernel<<<(N + 255) / 256, 256, 0, stream>>>(offsets, cursor, blockSums, N);
        place_kernel<<<(E + 255) / 256, 256, 0, stream>>>(src, dst, cursor, ssrc, E);
        agg_linear_kernel<<<2048, 256, 0, stream>>>(feat, ssrc, offsets, Wq, b, wcur, out, N);
    } else {
        const int n4 = N * (F / 4);
        zero_f4_kernel<<<(n4 + 255) / 256, 256, 0, stream>>>((float4*)out, n4);
        const int sthreads = E * 32;
        scatter_atomic_kernel<<<(sthreads + 255) / 256, 256, 0, stream>>>(feat, src, dst, out, E);
        linear_relu_w_kernel<<<(N + 63) / 64, 256, 0, stream>>>(out, W, b, N);
    }
}